// Round 6
// baseline (926.197 us; speedup 1.0000x reference)
//
#include <hip/hip_runtime.h>
#include <hip/hip_bf16.h>

// EdgeProbMLP: out[e] = sigmoid( relu( [x*y, x-y] @ W1.T + b1 ) @ W2.T + b2 )
// x = relu(nf[src] @ Wdim.T + bdim), y = same for dst.
// P[n] = relu(proj(nf[n])) precomputed once (bf16, d_ws); per-edge MFMA GEMM
// with W1 in LDS (bf16, XOR-swizzled).
// R6: 16x16x32 MFMA tiles (16 edges/wave-tile). Rationale from R5 counters:
// occupancy 11.4% == 1 wave/SIMD (256 VGPR + 64 acc on unified file), and
// 64-line-touch gather instructions. 16x16 halves acc (32) and row buffers
// (32: 4 lanes share an edge row, 64B contiguous per row per instr -> 16
// lines/instr), b1/W2 live in a 1KB LDS side-table (lgkm, not vmcnt) so the
// rotating prefetch never drains. 512-thr blocks, target <=128 VGPR -> 4
// waves/SIMD, 2 blocks/CU at 66KB LDS.

#define N_NODES 100000
#define N_EDGES 1000000
#define N_T16   62500     // 1M / 16

typedef unsigned int u32;
typedef u32   u32x2 __attribute__((ext_vector_type(2)));
typedef u32   u32x4 __attribute__((ext_vector_type(4)));
typedef float f32x4 __attribute__((ext_vector_type(4)));
typedef float f32x16 __attribute__((ext_vector_type(16)));
typedef __bf16 bf16x8 __attribute__((ext_vector_type(8)));

__device__ inline u32 pack2bf(float a, float b) {
    unsigned short ua = __builtin_bit_cast(unsigned short, (__bf16)a);
    unsigned short ub = __builtin_bit_cast(unsigned short, (__bf16)b);
    return (u32)ua | ((u32)ub << 16);
}
__device__ inline float bflo(u32 u) { return __builtin_bit_cast(float, u << 16); }
__device__ inline float bfhi(u32 u) { return __builtin_bit_cast(float, u & 0xFFFF0000u); }

// ---------------------------------------------------------------------------
// Kernel 1: P[n][c] = relu(sum_k nf[n][k] * Wdim[c][k] + bdim[c]), bf16 out.
// (unchanged from R5 — ~15us, not the bottleneck)
// ---------------------------------------------------------------------------
__global__ __launch_bounds__(256, 1) void k_project(
    const float* __restrict__ nf, const float* __restrict__ Wdim,
    const float* __restrict__ bdim, unsigned short* __restrict__ P)
{
    __shared__ unsigned char lA[128 * 256];  // 32 KB: Wdim as bf16 [128ch][128k]
    const int t = threadIdx.x;
    for (int ci = t; ci < 2048; ci += 256) {
        const int row = ci >> 4;
        const int k8 = (ci & 15) << 3;
        const float* wp = Wdim + (row << 7) + k8;
        f32x4 v0 = *(const f32x4*)wp;
        f32x4 v1 = *(const f32x4*)(wp + 4);
        u32x4 pk = { pack2bf(v0[0], v0[1]), pack2bf(v0[2], v0[3]),
                     pack2bf(v1[0], v1[1]), pack2bf(v1[2], v1[3]) };
        int byte = (row << 8) + (k8 << 1);
        byte ^= (row & 15) << 4;
        *(u32x4*)(lA + byte) = pk;
    }
    __syncthreads();

    const int lane = t & 63;
    const int wave = t >> 6;
    const int cc = lane & 31;
    const int h  = lane >> 5;
    const int tile = blockIdx.x * 4 + wave;
    if (tile >= 3125) return;
    const int node = (tile << 5) + cc;
    const float* xrow = nf + ((size_t)node << 7);

    f32x4 rv[16];
#pragma unroll
    for (int kt = 0; kt < 8; ++kt) {
        const int kf = (kt << 4) + (h << 3);
        rv[2*kt]   = *(const f32x4*)(xrow + kf);
        rv[2*kt+1] = *(const f32x4*)(xrow + kf + 4);
    }

    f32x16 acc[4] = {};
#pragma unroll
    for (int kt = 0; kt < 8; ++kt) {
        const int kf = (kt << 4) + (h << 3);
        f32x4 v0 = rv[2*kt], v1 = rv[2*kt+1];
        bf16x8 bf;
        bf[0]=(__bf16)v0[0]; bf[1]=(__bf16)v0[1]; bf[2]=(__bf16)v0[2]; bf[3]=(__bf16)v0[3];
        bf[4]=(__bf16)v1[0]; bf[5]=(__bf16)v1[1]; bf[6]=(__bf16)v1[2]; bf[7]=(__bf16)v1[3];
        const int off = kf << 1;
#pragma unroll
        for (int t4 = 0; t4 < 4; ++t4) {
            const int arow = (t4 << 5) + cc;
            const int ab = ((arow << 8) + off) ^ ((arow & 15) << 4);
            bf16x8 af = __builtin_bit_cast(bf16x8, *(const u32x4*)(lA + ab));
            acc[t4] = __builtin_amdgcn_mfma_f32_32x32x16_bf16(af, bf, acc[t4], 0, 0, 0);
        }
    }
    unsigned short* prow = P + ((size_t)node << 7);
#pragma unroll
    for (int t4 = 0; t4 < 4; ++t4) {
#pragma unroll
        for (int q = 0; q < 4; ++q) {
            const int chb = (t4 << 5) + (q << 3) + (h << 2);
            f32x4 bb = *(const f32x4*)(bdim + chb);
            const float h0 = fmaxf(acc[t4][(q << 2) + 0] + bb[0], 0.f);
            const float h1 = fmaxf(acc[t4][(q << 2) + 1] + bb[1], 0.f);
            const float h2 = fmaxf(acc[t4][(q << 2) + 2] + bb[2], 0.f);
            const float h3 = fmaxf(acc[t4][(q << 2) + 3] + bb[3], 0.f);
            u32x2 st = { pack2bf(h0, h1), pack2bf(h2, h3) };
            *(u32x2*)(prow + chb) = st;
        }
    }
}

// ---------------------------------------------------------------------------
// Kernel 2: per-edge MLP, 16 edges per wave-tile, 16x16x32 MFMA,
// rotating in-place prefetch, W1 + b1/W2 side-table in LDS.
// Fragment roles: A = W1 rows (ch), B = edge features.
//   lane l: ec = l&15 (edge / A-row low), q = l>>4 (k-quarter)
//   A/B k for MFMA step kt: k = kt*32 + q*8 + j  -> byte off = kt*64 + q*16
//   D: ch = cht*16 + q*4 + r, edge = ec
// ---------------------------------------------------------------------------
__global__ __launch_bounds__(512, 4) void k_edge(
    const unsigned short* __restrict__ P,
    const int* __restrict__ ei,          // [2][E] int32
    const float* __restrict__ W1, const float* __restrict__ b1,
    const float* __restrict__ W2, const float* __restrict__ b2,
    float* __restrict__ out)
{
    __shared__ unsigned char lA[128 * 512];  // 64 KB: W1 bf16 [128ch][256k]
    __shared__ u32 lB1[64];                  // b1 as bf16 pairs (ch 2i, 2i+1)
    __shared__ u32 lW2[64];                  // W2 as bf16 pairs
    const int t = threadIdx.x;               // 0..511
    for (int ci = t; ci < 4096; ci += 512) { // 4096 chunks of 16B
        const int row = ci >> 5;             // 32 chunks per 512B row
        const int c   = ci & 31;
        const float* wp = W1 + (row << 8) + (c << 3);
        f32x4 v0 = *(const f32x4*)wp;
        f32x4 v1 = *(const f32x4*)(wp + 4);
        u32x4 pk = { pack2bf(v0[0], v0[1]), pack2bf(v0[2], v0[3]),
                     pack2bf(v1[0], v1[1]), pack2bf(v1[2], v1[3]) };
        const int byte = (row << 9) + ((c ^ (row & 15)) << 4);
        *(u32x4*)(lA + byte) = pk;
    }
    if (t < 64) {
        lB1[t] = pack2bf(b1[2*t], b1[2*t+1]);
        lW2[t] = pack2bf(W2[2*t], W2[2*t+1]);
    }
    __syncthreads();

    const int lane = t & 63;
    const int wave = t >> 6;
    const int ec = lane & 15;     // edge column
    const int q  = lane >> 4;     // k-quarter
    const float b2v = b2[0];
    const int stride = gridDim.x << 3;                // total waves
    const int t0 = (blockIdx.x << 3) + wave;          // t0 < 4096 <= N_T16
    const unsigned char* Pb = (const unsigned char*)P;

    u32x4 xr[4], yr[4];           // rotation slots: this lane's row chunks
    int si, di;                   // node indices for NEXT tile
    {   // prologue: cold gather of tile t0, prefetch ei of t0+stride
        const int e0 = t0 << 4;
        const int s0 = ei[e0 + ec];
        const int d0 = ei[N_EDGES + e0 + ec];
        const unsigned char* ps = Pb + ((size_t)s0 << 8);
        const unsigned char* pd = Pb + ((size_t)d0 << 8);
#pragma unroll
        for (int kt = 0; kt < 4; ++kt) {
            const int off = (kt << 6) + (q << 4);
            xr[kt] = __builtin_nontemporal_load((const u32x4*)(ps + off));
            yr[kt] = __builtin_nontemporal_load((const u32x4*)(pd + off));
        }
        int tt = t0 + stride; tt = tt < N_T16 ? tt : N_T16 - 1;
        si = ei[(tt << 4) + ec];
        di = ei[N_EDGES + (tt << 4) + ec];
    }

    for (int tl = t0; tl < N_T16; tl += stride) {
        const unsigned char* nps = Pb + ((size_t)si << 8);
        const unsigned char* npd = Pb + ((size_t)di << 8);

        f32x4 acc[8] = {};
#pragma unroll
        for (int kt = 0; kt < 4; ++kt) {
            const int off = (kt << 6) + (q << 4);
            const u32x4 ux = xr[kt];
            const u32x4 uy = yr[kt];
            // rotate: refill dead slot with next tile's same chunk
            xr[kt] = __builtin_nontemporal_load((const u32x4*)(nps + off));
            yr[kt] = __builtin_nontemporal_load((const u32x4*)(npd + off));

            bf16x8 bp, bd;
#pragma unroll
            for (int j = 0; j < 4; ++j) {
                const float x0 = bflo(ux[j]), x1 = bfhi(ux[j]);
                const float y0 = bflo(uy[j]), y1 = bfhi(uy[j]);
                bp[2*j]   = (__bf16)(x0 * y0);
                bp[2*j+1] = (__bf16)(x1 * y1);
                bd[2*j]   = (__bf16)(x0 - y0);
                bd[2*j+1] = (__bf16)(x1 - y1);
            }
            const int cP = (kt << 2) + q;        // product chunk idx (0..15)
            const int cD = 16 + cP;              // diff chunk idx (16..31)
#pragma unroll
            for (int cht = 0; cht < 8; ++cht) {
                const int arow = (cht << 4) + ec;
                const int rb = arow << 9;
                const int sw = arow & 15;
                bf16x8 a1 = __builtin_bit_cast(bf16x8,
                    *(const u32x4*)(lA + rb + ((cP ^ sw) << 4)));
                acc[cht] = __builtin_amdgcn_mfma_f32_16x16x32_bf16(a1, bp, acc[cht], 0, 0, 0);
                bf16x8 a2 = __builtin_bit_cast(bf16x8,
                    *(const u32x4*)(lA + rb + ((cD ^ sw) << 4)));
                acc[cht] = __builtin_amdgcn_mfma_f32_16x16x32_bf16(a2, bd, acc[cht], 0, 0, 0);
            }
        }

        // epilogue: relu(+b1) . W2 from LDS side-table (lgkm only, no vmem)
        float partial = 0.f;
#pragma unroll
        for (int cht = 0; cht < 8; ++cht) {
            const int base = ((cht << 4) + (q << 2)) >> 1;   // ch pair index
#pragma unroll
            for (int rp = 0; rp < 2; ++rp) {
                const u32 bb = lB1[base + rp];
                const u32 ww = lW2[base + rp];
                const float h0 = fmaxf(acc[cht][2*rp]   + bflo(bb), 0.f);
                const float h1 = fmaxf(acc[cht][2*rp+1] + bfhi(bb), 0.f);
                partial += h0 * bflo(ww) + h1 * bfhi(ww);
            }
        }
        partial += __shfl_xor(partial, 16);       // sum quarters q^1
        partial += __shfl_xor(partial, 32);       // sum quarters q^2
        const float z = partial + b2v;
        const float prob = 1.0f / (1.0f + __expf(-z));
        if (q == 0) out[(tl << 4) + ec] = prob;

        // advance index prefetch: ei for tile tl + 2*stride
        int tt = tl + 2 * stride; tt = tt < N_T16 ? tt : N_T16 - 1;
        si = ei[(tt << 4) + ec];
        di = ei[N_EDGES + (tt << 4) + ec];
    }
}

extern "C" void kernel_launch(void* const* d_in, const int* in_sizes, int n_in,
                              void* d_out, int out_size, void* d_ws, size_t ws_size,
                              hipStream_t stream) {
    const float* nf   = (const float*)d_in[0];
    const int*   ei   = (const int*)d_in[1];
    const float* Wdim = (const float*)d_in[2];
    const float* bdim = (const float*)d_in[3];
    const float* W1   = (const float*)d_in[4];
    const float* b1   = (const float*)d_in[5];
    const float* W2   = (const float*)d_in[6];
    const float* b2   = (const float*)d_in[7];
    float* out = (float*)d_out;
    unsigned short* P = (unsigned short*)d_ws;        // 100000*128 bf16 = 25.6 MB

    k_project<<<dim3(782), dim3(256), 0, stream>>>(nf, Wdim, bdim, P);
    k_edge<<<dim3(512), dim3(512), 0, stream>>>(P, ei, W1, b1, W2, b2, out);
}

// Round 7
// 680.196 us; speedup vs baseline: 1.3617x; 1.3617x over previous
//
#include <hip/hip_runtime.h>
#include <hip/hip_bf16.h>

// EdgeProbMLP: out[e] = sigmoid( relu( [x*y, x-y] @ W1.T + b1 ) @ W2.T + b2 )
// x = relu(nf[src] @ Wdim.T + bdim), y = same for dst.
// P[n] = relu(proj(nf[n])) precomputed once (bf16, d_ws); per-edge MFMA GEMM
// with W1 in LDS (bf16, XOR-swizzled), 16 edges/wave-tile (16x16x32 MFMA),
// rotating in-place prefetch, b1/W2 in an LDS side-table.
// R7: R6 structure, launch_bounds fixed. R6's (512,4) made the allocator cap
// VGPR at 64 (observed rule: cap ~= 2048 / (waves_per_block * arg)) for a
// ~100-VGPR kernel -> 288MB/dispatch scratch, 900us. (512,2) gives cap >=128
// under either interpretation; LDS (64.5KB) then sets residency: 2 blocks/CU
// = 16 waves/CU = 4 waves/SIMD (4x R5).

#define N_NODES 100000
#define N_EDGES 1000000
#define N_T16   62500     // 1M / 16

typedef unsigned int u32;
typedef u32   u32x2 __attribute__((ext_vector_type(2)));
typedef u32   u32x4 __attribute__((ext_vector_type(4)));
typedef float f32x4 __attribute__((ext_vector_type(4)));
typedef float f32x16 __attribute__((ext_vector_type(16)));
typedef __bf16 bf16x8 __attribute__((ext_vector_type(8)));

__device__ inline u32 pack2bf(float a, float b) {
    unsigned short ua = __builtin_bit_cast(unsigned short, (__bf16)a);
    unsigned short ub = __builtin_bit_cast(unsigned short, (__bf16)b);
    return (u32)ua | ((u32)ub << 16);
}
__device__ inline float bflo(u32 u) { return __builtin_bit_cast(float, u << 16); }
__device__ inline float bfhi(u32 u) { return __builtin_bit_cast(float, u & 0xFFFF0000u); }

// ---------------------------------------------------------------------------
// Kernel 1: P[n][c] = relu(sum_k nf[n][k] * Wdim[c][k] + bdim[c]), bf16 out.
// (unchanged — ~15us, not the bottleneck)
// ---------------------------------------------------------------------------
__global__ __launch_bounds__(256, 1) void k_project(
    const float* __restrict__ nf, const float* __restrict__ Wdim,
    const float* __restrict__ bdim, unsigned short* __restrict__ P)
{
    __shared__ unsigned char lA[128 * 256];  // 32 KB: Wdim as bf16 [128ch][128k]
    const int t = threadIdx.x;
    for (int ci = t; ci < 2048; ci += 256) {
        const int row = ci >> 4;
        const int k8 = (ci & 15) << 3;
        const float* wp = Wdim + (row << 7) + k8;
        f32x4 v0 = *(const f32x4*)wp;
        f32x4 v1 = *(const f32x4*)(wp + 4);
        u32x4 pk = { pack2bf(v0[0], v0[1]), pack2bf(v0[2], v0[3]),
                     pack2bf(v1[0], v1[1]), pack2bf(v1[2], v1[3]) };
        int byte = (row << 8) + (k8 << 1);
        byte ^= (row & 15) << 4;
        *(u32x4*)(lA + byte) = pk;
    }
    __syncthreads();

    const int lane = t & 63;
    const int wave = t >> 6;
    const int cc = lane & 31;
    const int h  = lane >> 5;
    const int tile = blockIdx.x * 4 + wave;
    if (tile >= 3125) return;
    const int node = (tile << 5) + cc;
    const float* xrow = nf + ((size_t)node << 7);

    f32x4 rv[16];
#pragma unroll
    for (int kt = 0; kt < 8; ++kt) {
        const int kf = (kt << 4) + (h << 3);
        rv[2*kt]   = *(const f32x4*)(xrow + kf);
        rv[2*kt+1] = *(const f32x4*)(xrow + kf + 4);
    }

    f32x16 acc[4] = {};
#pragma unroll
    for (int kt = 0; kt < 8; ++kt) {
        const int kf = (kt << 4) + (h << 3);
        f32x4 v0 = rv[2*kt], v1 = rv[2*kt+1];
        bf16x8 bf;
        bf[0]=(__bf16)v0[0]; bf[1]=(__bf16)v0[1]; bf[2]=(__bf16)v0[2]; bf[3]=(__bf16)v0[3];
        bf[4]=(__bf16)v1[0]; bf[5]=(__bf16)v1[1]; bf[6]=(__bf16)v1[2]; bf[7]=(__bf16)v1[3];
        const int off = kf << 1;
#pragma unroll
        for (int t4 = 0; t4 < 4; ++t4) {
            const int arow = (t4 << 5) + cc;
            const int ab = ((arow << 8) + off) ^ ((arow & 15) << 4);
            bf16x8 af = __builtin_bit_cast(bf16x8, *(const u32x4*)(lA + ab));
            acc[t4] = __builtin_amdgcn_mfma_f32_32x32x16_bf16(af, bf, acc[t4], 0, 0, 0);
        }
    }
    unsigned short* prow = P + ((size_t)node << 7);
#pragma unroll
    for (int t4 = 0; t4 < 4; ++t4) {
#pragma unroll
        for (int q = 0; q < 4; ++q) {
            const int chb = (t4 << 5) + (q << 3) + (h << 2);
            f32x4 bb = *(const f32x4*)(bdim + chb);
            const float h0 = fmaxf(acc[t4][(q << 2) + 0] + bb[0], 0.f);
            const float h1 = fmaxf(acc[t4][(q << 2) + 1] + bb[1], 0.f);
            const float h2 = fmaxf(acc[t4][(q << 2) + 2] + bb[2], 0.f);
            const float h3 = fmaxf(acc[t4][(q << 2) + 3] + bb[3], 0.f);
            u32x2 st = { pack2bf(h0, h1), pack2bf(h2, h3) };
            *(u32x2*)(prow + chb) = st;
        }
    }
}

// ---------------------------------------------------------------------------
// Kernel 2: per-edge MLP, 16 edges per wave-tile, 16x16x32 MFMA,
// rotating in-place prefetch, W1 + b1/W2 side-table in LDS.
// Fragment roles: A = W1 rows (ch), B = edge features.
//   lane l: ec = l&15 (edge / A-row low), q = l>>4 (k-quarter)
//   A/B k for MFMA step kt: k = kt*32 + q*8 + j  -> byte off = kt*64 + q*16
//   D: ch = cht*16 + q*4 + r, edge = ec
// ---------------------------------------------------------------------------
__global__ __launch_bounds__(512, 2) void k_edge(
    const unsigned short* __restrict__ P,
    const int* __restrict__ ei,          // [2][E] int32
    const float* __restrict__ W1, const float* __restrict__ b1,
    const float* __restrict__ W2, const float* __restrict__ b2,
    float* __restrict__ out)
{
    __shared__ unsigned char lA[128 * 512];  // 64 KB: W1 bf16 [128ch][256k]
    __shared__ u32 lB1[64];                  // b1 as bf16 pairs (ch 2i, 2i+1)
    __shared__ u32 lW2[64];                  // W2 as bf16 pairs
    const int t = threadIdx.x;               // 0..511
    for (int ci = t; ci < 4096; ci += 512) { // 4096 chunks of 16B
        const int row = ci >> 5;             // 32 chunks per 512B row
        const int c   = ci & 31;
        const float* wp = W1 + (row << 8) + (c << 3);
        f32x4 v0 = *(const f32x4*)wp;
        f32x4 v1 = *(const f32x4*)(wp + 4);
        u32x4 pk = { pack2bf(v0[0], v0[1]), pack2bf(v0[2], v0[3]),
                     pack2bf(v1[0], v1[1]), pack2bf(v1[2], v1[3]) };
        const int byte = (row << 9) + ((c ^ (row & 15)) << 4);
        *(u32x4*)(lA + byte) = pk;
    }
    if (t < 64) {
        lB1[t] = pack2bf(b1[2*t], b1[2*t+1]);
        lW2[t] = pack2bf(W2[2*t], W2[2*t+1]);
    }
    __syncthreads();

    const int lane = t & 63;
    const int wave = t >> 6;
    const int ec = lane & 15;     // edge column
    const int q  = lane >> 4;     // k-quarter
    const float b2v = b2[0];
    const int stride = gridDim.x << 3;                // total waves
    const int t0 = (blockIdx.x << 3) + wave;          // t0 < 4096 <= N_T16
    const unsigned char* Pb = (const unsigned char*)P;

    u32x4 xr[4], yr[4];           // rotation slots: this lane's row chunks
    int si, di;                   // node indices for NEXT tile
    {   // prologue: cold gather of tile t0, prefetch ei of t0+stride
        const int e0 = t0 << 4;
        const int s0 = ei[e0 + ec];
        const int d0 = ei[N_EDGES + e0 + ec];
        const unsigned char* ps = Pb + ((size_t)s0 << 8);
        const unsigned char* pd = Pb + ((size_t)d0 << 8);
#pragma unroll
        for (int kt = 0; kt < 4; ++kt) {
            const int off = (kt << 6) + (q << 4);
            xr[kt] = __builtin_nontemporal_load((const u32x4*)(ps + off));
            yr[kt] = __builtin_nontemporal_load((const u32x4*)(pd + off));
        }
        int tt = t0 + stride; tt = tt < N_T16 ? tt : N_T16 - 1;
        si = ei[(tt << 4) + ec];
        di = ei[N_EDGES + (tt << 4) + ec];
    }

    for (int tl = t0; tl < N_T16; tl += stride) {
        const unsigned char* nps = Pb + ((size_t)si << 8);
        const unsigned char* npd = Pb + ((size_t)di << 8);

        f32x4 acc[8] = {};
#pragma unroll
        for (int kt = 0; kt < 4; ++kt) {
            const int off = (kt << 6) + (q << 4);
            const u32x4 ux = xr[kt];
            const u32x4 uy = yr[kt];
            // rotate: refill dead slot with next tile's same chunk
            xr[kt] = __builtin_nontemporal_load((const u32x4*)(nps + off));
            yr[kt] = __builtin_nontemporal_load((const u32x4*)(npd + off));

            bf16x8 bp, bd;
#pragma unroll
            for (int j = 0; j < 4; ++j) {
                const float x0 = bflo(ux[j]), x1 = bfhi(ux[j]);
                const float y0 = bflo(uy[j]), y1 = bfhi(uy[j]);
                bp[2*j]   = (__bf16)(x0 * y0);
                bp[2*j+1] = (__bf16)(x1 * y1);
                bd[2*j]   = (__bf16)(x0 - y0);
                bd[2*j+1] = (__bf16)(x1 - y1);
            }
            const int cP = (kt << 2) + q;        // product chunk idx (0..15)
            const int cD = 16 + cP;              // diff chunk idx (16..31)
#pragma unroll
            for (int cht = 0; cht < 8; ++cht) {
                const int arow = (cht << 4) + ec;
                const int rb = arow << 9;
                const int sw = arow & 15;
                bf16x8 a1 = __builtin_bit_cast(bf16x8,
                    *(const u32x4*)(lA + rb + ((cP ^ sw) << 4)));
                acc[cht] = __builtin_amdgcn_mfma_f32_16x16x32_bf16(a1, bp, acc[cht], 0, 0, 0);
                bf16x8 a2 = __builtin_bit_cast(bf16x8,
                    *(const u32x4*)(lA + rb + ((cD ^ sw) << 4)));
                acc[cht] = __builtin_amdgcn_mfma_f32_16x16x32_bf16(a2, bd, acc[cht], 0, 0, 0);
            }
        }

        // epilogue: relu(+b1) . W2 from LDS side-table (lgkm only, no vmem)
        float partial = 0.f;
#pragma unroll
        for (int cht = 0; cht < 8; ++cht) {
            const int base = ((cht << 4) + (q << 2)) >> 1;   // ch pair index
#pragma unroll
            for (int rp = 0; rp < 2; ++rp) {
                const u32 bb = lB1[base + rp];
                const u32 ww = lW2[base + rp];
                const float h0 = fmaxf(acc[cht][2*rp]   + bflo(bb), 0.f);
                const float h1 = fmaxf(acc[cht][2*rp+1] + bfhi(bb), 0.f);
                partial += h0 * bflo(ww) + h1 * bfhi(ww);
            }
        }
        partial += __shfl_xor(partial, 16);       // sum quarters q^1
        partial += __shfl_xor(partial, 32);       // sum quarters q^2
        const float z = partial + b2v;
        const float prob = 1.0f / (1.0f + __expf(-z));
        if (q == 0) out[(tl << 4) + ec] = prob;

        // advance index prefetch: ei for tile tl + 2*stride
        int tt = tl + 2 * stride; tt = tt < N_T16 ? tt : N_T16 - 1;
        si = ei[(tt << 4) + ec];
        di = ei[N_EDGES + (tt << 4) + ec];
    }
}

extern "C" void kernel_launch(void* const* d_in, const int* in_sizes, int n_in,
                              void* d_out, int out_size, void* d_ws, size_t ws_size,
                              hipStream_t stream) {
    const float* nf   = (const float*)d_in[0];
    const int*   ei   = (const int*)d_in[1];
    const float* Wdim = (const float*)d_in[2];
    const float* bdim = (const float*)d_in[3];
    const float* W1   = (const float*)d_in[4];
    const float* b1   = (const float*)d_in[5];
    const float* W2   = (const float*)d_in[6];
    const float* b2   = (const float*)d_in[7];
    float* out = (float*)d_out;
    unsigned short* P = (unsigned short*)d_ws;        // 100000*128 bf16 = 25.6 MB

    k_project<<<dim3(782), dim3(256), 0, stream>>>(nf, Wdim, bdim, P);
    k_edge<<<dim3(512), dim3(512), 0, stream>>>(P, ei, W1, b1, W2, b2, out);
}

// Round 9
// 218.966 us; speedup vs baseline: 4.2299x; 3.1064x over previous
//
#include <hip/hip_runtime.h>
#include <hip/hip_bf16.h>

// EdgeProbMLP: out[e] = sigmoid( relu( [x*y, x-y] @ W1.T + b1 ) @ W2.T + b2 )
// x = relu(nf[src] @ Wdim.T + bdim), y = same for dst.
// P[n] = relu(proj(nf[n])) precomputed once (bf16, d_ws); per-edge 32x32x16
// MFMA GEMM with W1 in LDS (bf16, XOR-swizzled), rotating in-place prefetch.
// R9: exact R5 source (best known-good, 273us) with ONE change: the P-row
// gathers use plain loads instead of __builtin_nontemporal_load. R8 bundled
// this with an LDS b1/W2 table and produced NaN (source audit found no bug;
// rollback to known-good + single variable). A/B question: does dropping nt
// let L2/L3 retain P (25.6MB, ~20 reads/node) -> FETCH collapse, or does it
// re-create R2's thrash (FETCH 1.45GB)? Branch B -> fp8 P demand reduction.

#define N_NODES 100000
#define N_EDGES 1000000
#define N_TILES 31250

typedef unsigned int u32;
typedef u32   u32x2 __attribute__((ext_vector_type(2)));
typedef u32   u32x4 __attribute__((ext_vector_type(4)));
typedef float f32x4 __attribute__((ext_vector_type(4)));
typedef float f32x16 __attribute__((ext_vector_type(16)));
typedef __bf16 bf16x8 __attribute__((ext_vector_type(8)));

__device__ inline u32 pack2bf(float a, float b) {
    unsigned short ua = __builtin_bit_cast(unsigned short, (__bf16)a);
    unsigned short ub = __builtin_bit_cast(unsigned short, (__bf16)b);
    return (u32)ua | ((u32)ub << 16);
}
__device__ inline float bflo(u32 u) { return __builtin_bit_cast(float, u << 16); }
__device__ inline float bfhi(u32 u) { return __builtin_bit_cast(float, u & 0xFFFF0000u); }

// ---------------------------------------------------------------------------
// Kernel 1: P[n][c] = relu(sum_k nf[n][k] * Wdim[c][k] + bdim[c]), bf16 out.
// ---------------------------------------------------------------------------
__global__ __launch_bounds__(256, 1) void k_project(
    const float* __restrict__ nf, const float* __restrict__ Wdim,
    const float* __restrict__ bdim, unsigned short* __restrict__ P)
{
    __shared__ unsigned char lA[128 * 256];  // 32 KB: Wdim as bf16 [128ch][128k]
    const int t = threadIdx.x;
    for (int ci = t; ci < 2048; ci += 256) {          // 2048 chunks of 8 elems
        const int row = ci >> 4;                      // 16 chunks per 128-elem row
        const int k8 = (ci & 15) << 3;
        const float* wp = Wdim + (row << 7) + k8;
        f32x4 v0 = *(const f32x4*)wp;
        f32x4 v1 = *(const f32x4*)(wp + 4);
        u32x4 pk = { pack2bf(v0[0], v0[1]), pack2bf(v0[2], v0[3]),
                     pack2bf(v1[0], v1[1]), pack2bf(v1[2], v1[3]) };
        int byte = (row << 8) + (k8 << 1);
        byte ^= (row & 15) << 4;
        *(u32x4*)(lA + byte) = pk;
    }
    __syncthreads();

    const int lane = t & 63;
    const int wave = t >> 6;
    const int cc = lane & 31;     // node column
    const int h  = lane >> 5;     // k-half within MFMA
    const int tile = blockIdx.x * 4 + wave;
    if (tile >= 3125) return;
    const int node = (tile << 5) + cc;
    const float* xrow = nf + ((size_t)node << 7);

    f32x4 rv[16];
#pragma unroll
    for (int kt = 0; kt < 8; ++kt) {
        const int kf = (kt << 4) + (h << 3);
        rv[2*kt]   = *(const f32x4*)(xrow + kf);
        rv[2*kt+1] = *(const f32x4*)(xrow + kf + 4);
    }

    f32x16 acc[4] = {};
#pragma unroll
    for (int kt = 0; kt < 8; ++kt) {                  // K = 128 = 8 * 16
        const int kf = (kt << 4) + (h << 3);
        f32x4 v0 = rv[2*kt], v1 = rv[2*kt+1];
        bf16x8 bf;
        bf[0]=(__bf16)v0[0]; bf[1]=(__bf16)v0[1]; bf[2]=(__bf16)v0[2]; bf[3]=(__bf16)v0[3];
        bf[4]=(__bf16)v1[0]; bf[5]=(__bf16)v1[1]; bf[6]=(__bf16)v1[2]; bf[7]=(__bf16)v1[3];
        const int off = kf << 1;                      // byte offset within LDS row
#pragma unroll
        for (int t4 = 0; t4 < 4; ++t4) {
            const int arow = (t4 << 5) + cc;
            const int ab = ((arow << 8) + off) ^ ((arow & 15) << 4);
            bf16x8 af = __builtin_bit_cast(bf16x8, *(const u32x4*)(lA + ab));
            acc[t4] = __builtin_amdgcn_mfma_f32_32x32x16_bf16(af, bf, acc[t4], 0, 0, 0);
        }
    }
    unsigned short* prow = P + ((size_t)node << 7);
#pragma unroll
    for (int t4 = 0; t4 < 4; ++t4) {
#pragma unroll
        for (int q = 0; q < 4; ++q) {
            const int chb = (t4 << 5) + (q << 3) + (h << 2);
            f32x4 bb = *(const f32x4*)(bdim + chb);
            const float h0 = fmaxf(acc[t4][(q << 2) + 0] + bb[0], 0.f);
            const float h1 = fmaxf(acc[t4][(q << 2) + 1] + bb[1], 0.f);
            const float h2 = fmaxf(acc[t4][(q << 2) + 2] + bb[2], 0.f);
            const float h3 = fmaxf(acc[t4][(q << 2) + 3] + bb[3], 0.f);
            u32x2 st = { pack2bf(h0, h1), pack2bf(h2, h3) };
            *(u32x2*)(prow + chb) = st;
        }
    }
}

// ---------------------------------------------------------------------------
// Kernel 2: per-edge MLP, 32 edges per wave-tile, rotating prefetch.
// ---------------------------------------------------------------------------
struct Rows { u32x4 v[16]; };   // [0..7]=src row chunks, [8..15]=dst row chunks

__global__ __launch_bounds__(256, 1) void k_edge(
    const unsigned short* __restrict__ P,
    const int* __restrict__ ei,          // [2][E] int32
    const float* __restrict__ W1, const float* __restrict__ b1,
    const float* __restrict__ W2, const float* __restrict__ b2,
    float* __restrict__ out)
{
    __shared__ unsigned char lA[128 * 512];  // 64 KB: W1 bf16 [128ch][256k]
    const int t = threadIdx.x;
    for (int ci = t; ci < 4096; ci += 256) {          // 4096 chunks of 8
        const int row = ci >> 5;                      // 32 chunks per 256-elem row
        const int k8 = (ci & 31) << 3;
        const float* wp = W1 + (row << 8) + k8;
        f32x4 v0 = *(const f32x4*)wp;
        f32x4 v1 = *(const f32x4*)(wp + 4);
        u32x4 pk = { pack2bf(v0[0], v0[1]), pack2bf(v0[2], v0[3]),
                     pack2bf(v1[0], v1[1]), pack2bf(v1[2], v1[3]) };
        int byte = (row << 9) + (k8 << 1);
        byte ^= (row & 31) << 4;
        *(u32x4*)(lA + byte) = pk;
    }
    __syncthreads();

    const int lane = t & 63;
    const int wave = t >> 6;
    const int cc = lane & 31;     // edge column within tile
    const int h  = lane >> 5;     // k-half
    const float b2v = b2[0];
    const int stride = gridDim.x << 2;
    const int t0 = blockIdx.x * 4 + wave;             // t0 < 2048 <= N_TILES

    // hoist b1 / W2 once: epilogue must issue ZERO per-tile vmem loads
    f32x4 b1h[16], w2h[16];
#pragma unroll
    for (int t4 = 0; t4 < 4; ++t4) {
#pragma unroll
        for (int q = 0; q < 4; ++q) {
            const int chb = (t4 << 5) + (q << 3) + (h << 2);
            b1h[(t4 << 2) + q] = *(const f32x4*)(b1 + chb);
            w2h[(t4 << 2) + q] = *(const f32x4*)(W2 + chb);
        }
    }

    Rows A;
    int si, di;                                       // indices for NEXT tile
    {   // prologue: cold gather of tile t0, prefetch ei of t0+stride
        const int e0 = t0 << 5;
        const int s0 = ei[e0 + cc];
        const int d0 = ei[N_EDGES + e0 + cc];
        const unsigned char* ps = (const unsigned char*)(P + ((size_t)s0 << 7));
        const unsigned char* pd = (const unsigned char*)(P + ((size_t)d0 << 7));
#pragma unroll
        for (int kt = 0; kt < 8; ++kt) {
            const int off = (kt << 5) + (h << 4);
            A.v[kt]     = *(const u32x4*)(ps + off);
            A.v[8 + kt] = *(const u32x4*)(pd + off);
        }
        int tt = t0 + stride; tt = tt < N_TILES ? tt : N_TILES - 1;
        si = ei[(tt << 5) + cc];
        di = ei[N_EDGES + (tt << 5) + cc];
    }

    for (int tl = t0; tl < N_TILES; tl += stride) {
        const unsigned char* nps = (const unsigned char*)(P + ((size_t)si << 7));
        const unsigned char* npd = (const unsigned char*)(P + ((size_t)di << 7));

        f32x16 acc[4] = {};
#pragma unroll
        for (int kt = 0; kt < 8; ++kt) {
            const int off = (kt << 5) + (h << 4);
            const u32x4 ux = A.v[kt];
            const u32x4 uy = A.v[8 + kt];
            // rotate: slot kt is dead after the copies above -> refill with
            // tile t+1's chunk kt. Issued ~8 MFMA-blocks before consumption.
            A.v[kt]     = *(const u32x4*)(nps + off);
            A.v[8 + kt] = *(const u32x4*)(npd + off);

            bf16x8 bp, bd;
#pragma unroll
            for (int j = 0; j < 4; ++j) {
                const float x0 = bflo(ux[j]), x1 = bfhi(ux[j]);
                const float y0 = bflo(uy[j]), y1 = bfhi(uy[j]);
                bp[2*j]   = (__bf16)(x0 * y0);
                bp[2*j+1] = (__bf16)(x1 * y1);
                bd[2*j]   = (__bf16)(x0 - y0);
                bd[2*j+1] = (__bf16)(x1 - y1);
            }
#pragma unroll
            for (int t4 = 0; t4 < 4; ++t4) {          // product half: W1[:,0:128]
                const int arow = (t4 << 5) + cc;
                const int ab = ((arow << 9) + off) ^ ((arow & 31) << 4);
                bf16x8 af = __builtin_bit_cast(bf16x8, *(const u32x4*)(lA + ab));
                acc[t4] = __builtin_amdgcn_mfma_f32_32x32x16_bf16(af, bp, acc[t4], 0, 0, 0);
            }
#pragma unroll
            for (int t4 = 0; t4 < 4; ++t4) {          // diff half: W1[:,128:256]
                const int arow = (t4 << 5) + cc;
                const int ab = ((arow << 9) + 256 + off) ^ ((arow & 31) << 4);
                bf16x8 af = __builtin_bit_cast(bf16x8, *(const u32x4*)(lA + ab));
                acc[t4] = __builtin_amdgcn_mfma_f32_32x32x16_bf16(af, bd, acc[t4], 0, 0, 0);
            }
        }

        // epilogue: pure VALU (no vmem loads) + one store
        float partial = 0.f;
#pragma unroll
        for (int t4 = 0; t4 < 4; ++t4) {
#pragma unroll
            for (int q = 0; q < 4; ++q) {
                const f32x4 bb = b1h[(t4 << 2) + q];
                const f32x4 ww = w2h[(t4 << 2) + q];
#pragma unroll
                for (int rr = 0; rr < 4; ++rr) {
                    const float hv = fmaxf(acc[t4][(q << 2) + rr] + bb[rr], 0.f);
                    partial += hv * ww[rr];
                }
            }
        }
        partial += __shfl_xor(partial, 32);           // sum the two k-half groups
        const float z = partial + b2v;
        const float prob = 1.0f / (1.0f + __expf(-z));
        if (h == 0) out[(tl << 5) + cc] = prob;

        // advance index prefetch: ei for tile tl + 2*stride
        int tt = tl + 2 * stride; tt = tt < N_TILES ? tt : N_TILES - 1;
        si = ei[(tt << 5) + cc];
        di = ei[N_EDGES + (tt << 5) + cc];
    }
}

extern "C" void kernel_launch(void* const* d_in, const int* in_sizes, int n_in,
                              void* d_out, int out_size, void* d_ws, size_t ws_size,
                              hipStream_t stream) {
    const float* nf   = (const float*)d_in[0];
    const int*   ei   = (const int*)d_in[1];
    const float* Wdim = (const float*)d_in[2];
    const float* bdim = (const float*)d_in[3];
    const float* W1   = (const float*)d_in[4];
    const float* b1   = (const float*)d_in[5];
    const float* W2   = (const float*)d_in[6];
    const float* b2   = (const float*)d_in[7];
    float* out = (float*)d_out;
    unsigned short* P = (unsigned short*)d_ws;        // 100000*128 bf16 = 25.6 MB

    k_project<<<dim3(782), dim3(256), 0, stream>>>(nf, Wdim, bdim, P);
    k_edge<<<dim3(512), dim3(256), 0, stream>>>(P, ei, W1, b1, W2, b2, out);
}